// Round 9
// baseline (390.684 us; speedup 1.0000x reference)
//
#include <hip/hip_runtime.h>
#include <hip/hip_bf16.h>
#include <cstdint>
#include <cstddef>

#define B_  4
#define T_  2048
#define D_  1024
#define H_  16
#define DK_ 64
#define M_  (B_ * T_)     // 8192 tokens

typedef __attribute__((ext_vector_type(8))) short bf16x8;   // MFMA A/B frag (4 VGPRs)
typedef __attribute__((ext_vector_type(4))) float f32x4;    // MFMA C/D frag

static __device__ __forceinline__ unsigned short f2bf(float f) {
    __hip_bfloat16 h = __float2bfloat16(f);
    unsigned short u;
    __builtin_memcpy(&u, &h, 2);
    return u;
}

static __device__ __forceinline__ void gl2lds16(const void* g, void* l) {
    __builtin_amdgcn_global_load_lds(
        (const __attribute__((address_space(1))) unsigned int*)g,
        (__attribute__((address_space(3))) unsigned int*)l,
        16, 0, 0);
}

// ---------------------------------------------------------------------------
// fp32 -> bf16 convert: regions [x | wq | wk | wv | wo] -> contiguous dst.
// ---------------------------------------------------------------------------
__global__ __launch_bounds__(256) void cvt_bf16(
    const float* __restrict__ x,  const float* __restrict__ wq,
    const float* __restrict__ wk, const float* __restrict__ wv,
    const float* __restrict__ wo, unsigned short* __restrict__ dst)
{
    const int idx = blockIdx.x * 256 + threadIdx.x;   // vec4 index
    const float* src;
    int off;
    if (idx < 2097152) { src = x; off = idx; }
    else {
        const int r = (idx - 2097152) >> 18;
        off = (idx - 2097152) & 262143;
        src = (r == 0) ? wq : (r == 1) ? wk : (r == 2) ? wv : wo;
    }
    float4 v = ((const float4*)src)[off];
    ushort4 o;
    o.x = f2bf(v.x); o.y = f2bf(v.y); o.z = f2bf(v.z); o.w = f2bf(v.w);
    ((ushort4*)dst)[idx] = o;
}

// ---------------------------------------------------------------------------
// QKV MFMA GEMM (m97 structure), 128x128 tile, BK=32.
// Q epilogue folds 1/sqrt(DK) * log2(e) so attention can use raw exp2.
// ---------------------------------------------------------------------------
__global__ __launch_bounds__(256) void qkv_gemm(
    const unsigned short* __restrict__ xb,
    const unsigned short* __restrict__ wqb, const unsigned short* __restrict__ wkb,
    const unsigned short* __restrict__ wvb,
    const float* __restrict__ bq, const float* __restrict__ bk,
    const float* __restrict__ bv,
    unsigned short* __restrict__ qkv_out)
{
    const int sel = blockIdx.z;
    const unsigned short* wb = (sel == 0) ? wqb : (sel == 1) ? wkb : wvb;
    const float* bias        = (sel == 0) ? bq  : (sel == 1) ? bk  : bv;
    const float osc          = (sel == 0) ? 0.125f * 1.44269504f : 1.0f;

    const int m0 = blockIdx.x * 128;
    const int n0 = blockIdx.y * 128;
    const int tid = threadIdx.x;
    const int w = tid >> 6, lane = tid & 63;
    const int l15 = lane & 15, g = lane >> 4;

    __shared__ __align__(16) unsigned short Af[8][512];
    __shared__ __align__(16) unsigned short Bf[8][512];

    f32x4 acc[4][4];
#pragma unroll
    for (int i = 0; i < 4; ++i)
#pragma unroll
        for (int j = 0; j < 4; ++j) acc[i][j] = (f32x4){0.f, 0.f, 0.f, 0.f};

    const int wm = (w & 1) * 4;
    const int wn = (w >> 1) * 4;

    const unsigned short* aSrc0 = xb + (size_t)(m0 + (w * 2    ) * 16 + l15) * D_ + g * 8;
    const unsigned short* aSrc1 = xb + (size_t)(m0 + (w * 2 + 1) * 16 + l15) * D_ + g * 8;
    const unsigned short* bSrc0 = wb + (size_t)(n0 + (w * 2    ) * 16 + l15) * D_ + g * 8;
    const unsigned short* bSrc1 = wb + (size_t)(n0 + (w * 2 + 1) * 16 + l15) * D_ + g * 8;

    for (int k0 = 0; k0 < D_; k0 += 32) {
        __syncthreads();
        gl2lds16(aSrc0 + k0, &Af[w * 2    ][0]);
        gl2lds16(aSrc1 + k0, &Af[w * 2 + 1][0]);
        gl2lds16(bSrc0 + k0, &Bf[w * 2    ][0]);
        gl2lds16(bSrc1 + k0, &Bf[w * 2 + 1][0]);
        __syncthreads();

        bf16x8 af[4], bf[4];
#pragma unroll
        for (int i = 0; i < 4; ++i) af[i] = *(const bf16x8*)&Af[wm + i][lane * 8];
#pragma unroll
        for (int j = 0; j < 4; ++j) bf[j] = *(const bf16x8*)&Bf[wn + j][lane * 8];

        if (sel < 2) {
#pragma unroll
            for (int i = 0; i < 4; ++i)
#pragma unroll
                for (int j = 0; j < 4; ++j)
                    acc[i][j] = __builtin_amdgcn_mfma_f32_16x16x32_bf16(
                        bf[i], af[j], acc[i][j], 0, 0, 0);
        } else {
#pragma unroll
            for (int i = 0; i < 4; ++i)
#pragma unroll
                for (int j = 0; j < 4; ++j)
                    acc[i][j] = __builtin_amdgcn_mfma_f32_16x16x32_bf16(
                        af[i], bf[j], acc[i][j], 0, 0, 0);
        }
    }

    const size_t BTD = (size_t)B_ * T_ * D_;
    if (sel < 2) {
        unsigned short* out = qkv_out + (size_t)sel * BTD;
#pragma unroll
        for (int i = 0; i < 4; ++i) {
            const int ch0 = n0 + (wn + i) * 16 + g * 4;
            const int h   = ch0 >> 6;
            const int dk0 = ch0 & 63;
            float4 bb = *(const float4*)(bias + ch0);
#pragma unroll
            for (int j = 0; j < 4; ++j) {
                const int tok = m0 + (wm + j) * 16 + l15;
                const int b = tok >> 11, t = tok & (T_ - 1);
                ushort4 r;
                r.x = f2bf((acc[i][j][0] + bb.x) * osc);
                r.y = f2bf((acc[i][j][1] + bb.y) * osc);
                r.z = f2bf((acc[i][j][2] + bb.z) * osc);
                r.w = f2bf((acc[i][j][3] + bb.w) * osc);
                *(ushort4*)(out + ((size_t)((b * H_ + h) * T_ + t)) * DK_ + dk0) = r;
            }
        }
    } else {
        unsigned short* out = qkv_out + 2 * BTD;   // Vt [bh][dk][t]
#pragma unroll
        for (int j = 0; j < 4; ++j) {
            const int ch = n0 + (wn + j) * 16 + l15;
            const int h  = ch >> 6;
            const int dk = ch & 63;
            const float bb = bias[ch];
#pragma unroll
            for (int i = 0; i < 4; ++i) {
                const int tok0 = m0 + (wm + i) * 16 + g * 4;
                const int b = tok0 >> 11, t0 = tok0 & (T_ - 1);
                ushort4 r;
                r.x = f2bf(acc[i][j][0] + bb);
                r.y = f2bf(acc[i][j][1] + bb);
                r.z = f2bf(acc[i][j][2] + bb);
                r.w = f2bf(acc[i][j][3] + bb);
                *(ushort4*)(out + ((size_t)((b * H_ + h) * DK_ + dk)) * T_ + t0) = r;
            }
        }
    }
}

// ---------------------------------------------------------------------------
// MFMA flash attention, R8: 128 q-rows / block (4 waves x 2 Q-frags), 64-key
// chunks, register-prefetch staging. Per chunk: same barrier/staging/LDS-read
// cost as R7 but 32 MFMA instead of 16 — overhead amortized 2x. Frag A is
// block-uniformly dead in the final (diagonal-B) chunk and skipped.
// Fixed-base softmax with exp2 (log2e folded into Q). grid.x reversed.
// ---------------------------------------------------------------------------
__global__ __launch_bounds__(256) void attn(
    const unsigned short* __restrict__ qg, const unsigned short* __restrict__ kg,
    const unsigned short* __restrict__ vtg, unsigned short* __restrict__ yh)
{
    const int bh  = blockIdx.y;
    const int h   = bh & (H_ - 1);
    const int b   = bh >> 4;
    const int tq0 = ((int)gridDim.x - 1 - (int)blockIdx.x) * 128;
    const int tid  = threadIdx.x;
    const int w    = tid >> 6;
    const int lane = tid & 63;
    const int l15  = lane & 15;
    const int g    = lane >> 4;

    const size_t base = (size_t)bh * T_ * DK_;
    const unsigned short* Qb  = qg  + base;   // [t][dk], pre-scaled
    const unsigned short* Kb  = kg  + base;   // [t][dk]
    const unsigned short* Vtb = vtg + base;   // [dk][t]

    __shared__ __align__(16) unsigned short Kf[8][512];        // 8 KB
    __shared__ __align__(16) unsigned short Vf[8][512];        // 8 KB
    __shared__ __align__(16) unsigned short Pb[4][2][16][68];  // 17.4 KB (0-conflict)

    const int qA = tq0 + w * 16;              // frag A q-base (rows qA..qA+15)
    const int qB = qA + 64;                   // frag B q-base
    const int tqA = qA + l15;
    const int tqB = qB + l15;

    bf16x8 qfA0 = *(const bf16x8*)(Qb + (size_t)tqA * DK_ + g * 8);
    bf16x8 qfA1 = *(const bf16x8*)(Qb + (size_t)tqA * DK_ + 32 + g * 8);
    bf16x8 qfB0 = *(const bf16x8*)(Qb + (size_t)tqB * DK_ + g * 8);
    bf16x8 qfB1 = *(const bf16x8*)(Qb + (size_t)tqB * DK_ + 32 + g * 8);

    f32x4 oA[4], oB[4];
#pragma unroll
    for (int i = 0; i < 4; ++i) {
        oA[i] = (f32x4){0.f, 0.f, 0.f, 0.f};
        oB[i] = (f32x4){0.f, 0.f, 0.f, 0.f};
    }
    float lA = 0.f, lB = 0.f;

    // wave w stages K s-tile st=w and V d-tile dt=w (both 32-wide halves)
    const unsigned short* kSrc = Kb + (size_t)(w * 16 + l15) * DK_ + g * 8;
    const unsigned short* vSrc = Vtb + (size_t)(w * 16 + l15) * T_ + g * 8;

    const int nCh = tq0 / 64 + 2;

    // preload chunk 0 into registers
    bf16x8 kr0 = *(const bf16x8*)(kSrc);
    bf16x8 kr1 = *(const bf16x8*)(kSrc + 32);
    bf16x8 vr0 = *(const bf16x8*)(vSrc);
    bf16x8 vr1 = *(const bf16x8*)(vSrc + 32);

    for (int ch = 0; ch < nCh; ++ch) {
        const int s0 = ch * 64;
        __syncthreads();                       // previous chunk fully consumed
        *(bf16x8*)&Kf[2 * w    ][lane * 8] = kr0;
        *(bf16x8*)&Kf[2 * w + 1][lane * 8] = kr1;
        *(bf16x8*)&Vf[2 * w    ][lane * 8] = vr0;
        *(bf16x8*)&Vf[2 * w + 1][lane * 8] = vr1;
        if (ch + 1 < nCh) {                    // loads stay in flight across barrier
            const size_t ko = (size_t)(s0 + 64) * DK_;
            kr0 = *(const bf16x8*)(kSrc + ko);
            kr1 = *(const bf16x8*)(kSrc + ko + 32);
            vr0 = *(const bf16x8*)(vSrc + s0 + 64);
            vr1 = *(const bf16x8*)(vSrc + s0 + 96);
        }
        __syncthreads();                       // staged data visible

        const bool liveA = (ch != nCh - 1);    // block-uniform: A dead only in last chunk
        float psA = 0.f, psB = 0.f;

#pragma unroll
        for (int st = 0; st < 4; ++st) {
            const int sbase = s0 + st * 16;
            bf16x8 a0 = *(const bf16x8*)&Kf[st * 2 + 0][lane * 8];
            bf16x8 a1 = *(const bf16x8*)&Kf[st * 2 + 1][lane * 8];

            // ---- frag B (live in every chunk) ----
            {
                ushort4 pk;
                if (sbase <= qB + 15) {
                    f32x4 sacc = {0.f, 0.f, 0.f, 0.f};
                    sacc = __builtin_amdgcn_mfma_f32_16x16x32_bf16(a0, qfB0, sacc, 0, 0, 0);
                    sacc = __builtin_amdgcn_mfma_f32_16x16x32_bf16(a1, qfB1, sacc, 0, 0, 0);
                    float p0, p1, p2, p3;
                    if (sbase + 15 > qB) {
                        p0 = (sbase + g * 4 + 0 <= tqB) ? exp2f(sacc[0]) : 0.f;
                        p1 = (sbase + g * 4 + 1 <= tqB) ? exp2f(sacc[1]) : 0.f;
                        p2 = (sbase + g * 4 + 2 <= tqB) ? exp2f(sacc[2]) : 0.f;
                        p3 = (sbase + g * 4 + 3 <= tqB) ? exp2f(sacc[3]) : 0.f;
                    } else {
                        p0 = exp2f(sacc[0]); p1 = exp2f(sacc[1]);
                        p2 = exp2f(sacc[2]); p3 = exp2f(sacc[3]);
                    }
                    psB += (p0 + p1) + (p2 + p3);
                    pk.x = f2bf(p0); pk.y = f2bf(p1); pk.z = f2bf(p2); pk.w = f2bf(p3);
                } else {
                    pk.x = 0; pk.y = 0; pk.z = 0; pk.w = 0;
                }
                *(ushort4*)&Pb[w][1][l15][st * 16 + g * 4] = pk;
            }

            // ---- frag A ----
            if (liveA) {
                ushort4 pk;
                if (sbase <= qA + 15) {
                    f32x4 sacc = {0.f, 0.f, 0.f, 0.f};
                    sacc = __builtin_amdgcn_mfma_f32_16x16x32_bf16(a0, qfA0, sacc, 0, 0, 0);
                    sacc = __builtin_amdgcn_mfma_f32_16x16x32_bf16(a1, qfA1, sacc, 0, 0, 0);
                    float p0, p1, p2, p3;
                    if (sbase + 15 > qA) {
                        p0 = (sbase + g * 4 + 0 <= tqA) ? exp2f(sacc[0]) : 0.f;
                        p1 = (sbase + g * 4 + 1 <= tqA) ? exp2f(sacc[1]) : 0.f;
                        p2 = (sbase + g * 4 + 2 <= tqA) ? exp2f(sacc[2]) : 0.f;
                        p3 = (sbase + g * 4 + 3 <= tqA) ? exp2f(sacc[3]) : 0.f;
                    } else {
                        p0 = exp2f(sacc[0]); p1 = exp2f(sacc[1]);
                        p2 = exp2f(sacc[2]); p3 = exp2f(sacc[3]);
                    }
                    psA += (p0 + p1) + (p2 + p3);
                    pk.x = f2bf(p0); pk.y = f2bf(p1); pk.z = f2bf(p2); pk.w = f2bf(p3);
                } else {
                    pk.x = 0; pk.y = 0; pk.z = 0; pk.w = 0;
                }
                *(ushort4*)&Pb[w][0][l15][st * 16 + g * 4] = pk;
            }
        }

        psB += __shfl_xor(psB, 16, 64);
        psB += __shfl_xor(psB, 32, 64);
        lB += psB;
        if (liveA) {
            psA += __shfl_xor(psA, 16, 64);
            psA += __shfl_xor(psA, 32, 64);
            lA += psA;
        }

        // ---- PV: O^T += V^T . P^T, both frags share V reads ----
        bf16x8 pfB0 = *(const bf16x8*)&Pb[w][1][l15][g * 8];
        bf16x8 pfB1 = *(const bf16x8*)&Pb[w][1][l15][32 + g * 8];
        if (liveA) {
            bf16x8 pfA0 = *(const bf16x8*)&Pb[w][0][l15][g * 8];
            bf16x8 pfA1 = *(const bf16x8*)&Pb[w][0][l15][32 + g * 8];
#pragma unroll
            for (int dt = 0; dt < 4; ++dt) {
                bf16x8 v0 = *(const bf16x8*)&Vf[dt * 2 + 0][lane * 8];
                bf16x8 v1 = *(const bf16x8*)&Vf[dt * 2 + 1][lane * 8];
                oB[dt] = __builtin_amdgcn_mfma_f32_16x16x32_bf16(v0, pfB0, oB[dt], 0, 0, 0);
                oB[dt] = __builtin_amdgcn_mfma_f32_16x16x32_bf16(v1, pfB1, oB[dt], 0, 0, 0);
                oA[dt] = __builtin_amdgcn_mfma_f32_16x16x32_bf16(v0, pfA0, oA[dt], 0, 0, 0);
                oA[dt] = __builtin_amdgcn_mfma_f32_16x16x32_bf16(v1, pfA1, oA[dt], 0, 0, 0);
            }
        } else {
#pragma unroll
            for (int dt = 0; dt < 4; ++dt) {
                bf16x8 v0 = *(const bf16x8*)&Vf[dt * 2 + 0][lane * 8];
                bf16x8 v1 = *(const bf16x8*)&Vf[dt * 2 + 1][lane * 8];
                oB[dt] = __builtin_amdgcn_mfma_f32_16x16x32_bf16(v0, pfB0, oB[dt], 0, 0, 0);
                oB[dt] = __builtin_amdgcn_mfma_f32_16x16x32_bf16(v1, pfB1, oB[dt], 0, 0, 0);
            }
        }
    }

    const float invA = 1.f / lA;
    const float invB = 1.f / lB;
    unsigned short* yrowA = yh + ((size_t)(b * T_ + tqA)) * D_ + h * DK_;
    unsigned short* yrowB = yh + ((size_t)(b * T_ + tqB)) * D_ + h * DK_;
#pragma unroll
    for (int dt = 0; dt < 4; ++dt) {
        ushort4 r;
        r.x = f2bf(oA[dt][0] * invA); r.y = f2bf(oA[dt][1] * invA);
        r.z = f2bf(oA[dt][2] * invA); r.w = f2bf(oA[dt][3] * invA);
        *(ushort4*)(yrowA + dt * 16 + g * 4) = r;
        r.x = f2bf(oB[dt][0] * invB); r.y = f2bf(oB[dt][1] * invB);
        r.z = f2bf(oB[dt][2] * invB); r.w = f2bf(oB[dt][3] * invB);
        *(ushort4*)(yrowB + dt * 16 + g * 4) = r;
    }
}

// ---------------------------------------------------------------------------
// Output MFMA GEMM: out[tok][ch] fp32 = yhb . wob^T + bo. (unchanged)
// ---------------------------------------------------------------------------
__global__ __launch_bounds__(256) void out_gemm(
    const unsigned short* __restrict__ yhb, const unsigned short* __restrict__ wob,
    const float* __restrict__ bo, float* __restrict__ out)
{
    const int m0 = blockIdx.x * 128;
    const int n0 = blockIdx.y * 128;
    const int tid = threadIdx.x;
    const int w = tid >> 6, lane = tid & 63;
    const int l15 = lane & 15, g = lane >> 4;

    __shared__ __align__(16) unsigned short Af[8][512];
    __shared__ __align__(16) unsigned short Bf[8][512];

    f32x4 acc[4][4];
#pragma unroll
    for (int i = 0; i < 4; ++i)
#pragma unroll
        for (int j = 0; j < 4; ++j) acc[i][j] = (f32x4){0.f, 0.f, 0.f, 0.f};

    const int wm = (w & 1) * 4;
    const int wn = (w >> 1) * 4;

    const unsigned short* aSrc0 = yhb + (size_t)(m0 + (w * 2    ) * 16 + l15) * D_ + g * 8;
    const unsigned short* aSrc1 = yhb + (size_t)(m0 + (w * 2 + 1) * 16 + l15) * D_ + g * 8;
    const unsigned short* bSrc0 = wob + (size_t)(n0 + (w * 2    ) * 16 + l15) * D_ + g * 8;
    const unsigned short* bSrc1 = wob + (size_t)(n0 + (w * 2 + 1) * 16 + l15) * D_ + g * 8;

    for (int k0 = 0; k0 < D_; k0 += 32) {
        __syncthreads();
        gl2lds16(aSrc0 + k0, &Af[w * 2    ][0]);
        gl2lds16(aSrc1 + k0, &Af[w * 2 + 1][0]);
        gl2lds16(bSrc0 + k0, &Bf[w * 2    ][0]);
        gl2lds16(bSrc1 + k0, &Bf[w * 2 + 1][0]);
        __syncthreads();

        bf16x8 af[4], bf[4];
#pragma unroll
        for (int i = 0; i < 4; ++i) af[i] = *(const bf16x8*)&Af[wm + i][lane * 8];
#pragma unroll
        for (int j = 0; j < 4; ++j) bf[j] = *(const bf16x8*)&Bf[wn + j][lane * 8];

#pragma unroll
        for (int i = 0; i < 4; ++i)
#pragma unroll
            for (int j = 0; j < 4; ++j)
                acc[i][j] = __builtin_amdgcn_mfma_f32_16x16x32_bf16(
                    bf[i], af[j], acc[i][j], 0, 0, 0);
    }

#pragma unroll
    for (int i = 0; i < 4; ++i) {
        const int ch0 = n0 + (wn + i) * 16 + g * 4;
        float4 bb = *(const float4*)(bo + ch0);
#pragma unroll
        for (int j = 0; j < 4; ++j) {
            const int tok = m0 + (wm + j) * 16 + l15;
            float4 r;
            r.x = acc[i][j][0] + bb.x;
            r.y = acc[i][j][1] + bb.y;
            r.z = acc[i][j][2] + bb.z;
            r.w = acc[i][j][3] + bb.w;
            *(float4*)(out + (size_t)tok * D_ + ch0) = r;
        }
    }
}

// ---------------------------------------------------------------------------
extern "C" void kernel_launch(void* const* d_in, const int* in_sizes, int n_in,
                              void* d_out, int out_size, void* d_ws, size_t ws_size,
                              hipStream_t stream) {
    const float* x  = (const float*)d_in[0];
    const float* wq = (const float*)d_in[1];
    const float* bq = (const float*)d_in[2];
    const float* wk = (const float*)d_in[3];
    const float* bk = (const float*)d_in[4];
    const float* wv = (const float*)d_in[5];
    const float* bv = (const float*)d_in[6];
    const float* wo = (const float*)d_in[7];
    const float* bo = (const float*)d_in[8];
    float* out = (float*)d_out;

    const size_t BTD = (size_t)B_ * T_ * D_;          // 8388608
    const size_t WSZ = (size_t)D_ * D_;               // 1048576
    unsigned short* xb  = (unsigned short*)d_ws;      // [x | wq | wk | wv | wo] bf16
    unsigned short* wqb = xb  + BTD;
    unsigned short* wkb = wqb + WSZ;
    unsigned short* wvb = wkb + WSZ;
    unsigned short* wob = wvb + WSZ;
    unsigned short* qb  = wob + WSZ;                  // q | k | vt bf16
    unsigned short* kb  = qb  + BTD;
    unsigned short* vtb = kb  + BTD;
    unsigned short* yhb = vtb + BTD;                  // yh bf16 [B,T,D]

    cvt_bf16<<<dim3(12288), 256, 0, stream>>>(x, wq, wk, wv, wo, xb);

    dim3 g1(M_ / 128, D_ / 128, 3);
    qkv_gemm<<<g1, 256, 0, stream>>>(xb, wqb, wkb, wvb, bq, bk, bv, qb);

    dim3 g2(T_ / 128, B_ * H_);                       // 16 x 64 = 1024 blocks
    attn<<<g2, 256, 0, stream>>>(qb, kb, vtb, yhb);

    dim3 g3(M_ / 128, D_ / 128);
    out_gemm<<<g3, 256, 0, stream>>>(yhb, wob, bo, out);
}

// Round 10
// 360.316 us; speedup vs baseline: 1.0843x; 1.0843x over previous
//
#include <hip/hip_runtime.h>
#include <hip/hip_bf16.h>
#include <cstdint>
#include <cstddef>

#define B_  4
#define T_  2048
#define D_  1024
#define H_  16
#define DK_ 64
#define M_  (B_ * T_)     // 8192 tokens

typedef __attribute__((ext_vector_type(8))) short bf16x8;   // MFMA A/B frag (4 VGPRs)
typedef __attribute__((ext_vector_type(4))) float f32x4;    // MFMA C/D frag

static __device__ __forceinline__ unsigned short f2bf(float f) {
    __hip_bfloat16 h = __float2bfloat16(f);
    unsigned short u;
    __builtin_memcpy(&u, &h, 2);
    return u;
}

static __device__ __forceinline__ void gl2lds16(const void* g, void* l) {
    __builtin_amdgcn_global_load_lds(
        (const __attribute__((address_space(1))) unsigned int*)g,
        (__attribute__((address_space(3))) unsigned int*)l,
        16, 0, 0);
}

// ---------------------------------------------------------------------------
// fp32 -> bf16 convert: regions [x | wq | wk | wv | wo] -> contiguous dst.
// ---------------------------------------------------------------------------
__global__ __launch_bounds__(256) void cvt_bf16(
    const float* __restrict__ x,  const float* __restrict__ wq,
    const float* __restrict__ wk, const float* __restrict__ wv,
    const float* __restrict__ wo, unsigned short* __restrict__ dst)
{
    const int idx = blockIdx.x * 256 + threadIdx.x;   // vec4 index
    const float* src;
    int off;
    if (idx < 2097152) { src = x; off = idx; }
    else {
        const int r = (idx - 2097152) >> 18;
        off = (idx - 2097152) & 262143;
        src = (r == 0) ? wq : (r == 1) ? wk : (r == 2) ? wv : wo;
    }
    float4 v = ((const float4*)src)[off];
    ushort4 o;
    o.x = f2bf(v.x); o.y = f2bf(v.y); o.z = f2bf(v.z); o.w = f2bf(v.w);
    ((ushort4*)dst)[idx] = o;
}

// ---------------------------------------------------------------------------
// QKV MFMA GEMM (m97 structure), 128x128 tile, BK=32.
// Q epilogue folds 1/sqrt(DK) * log2(e) so attention uses raw exp2.
// ---------------------------------------------------------------------------
__global__ __launch_bounds__(256) void qkv_gemm(
    const unsigned short* __restrict__ xb,
    const unsigned short* __restrict__ wqb, const unsigned short* __restrict__ wkb,
    const unsigned short* __restrict__ wvb,
    const float* __restrict__ bq, const float* __restrict__ bk,
    const float* __restrict__ bv,
    unsigned short* __restrict__ qkv_out)
{
    const int sel = blockIdx.z;
    const unsigned short* wb = (sel == 0) ? wqb : (sel == 1) ? wkb : wvb;
    const float* bias        = (sel == 0) ? bq  : (sel == 1) ? bk  : bv;
    const float osc          = (sel == 0) ? 0.125f * 1.44269504f : 1.0f;

    const int m0 = blockIdx.x * 128;
    const int n0 = blockIdx.y * 128;
    const int tid = threadIdx.x;
    const int w = tid >> 6, lane = tid & 63;
    const int l15 = lane & 15, g = lane >> 4;

    __shared__ __align__(16) unsigned short Af[8][512];
    __shared__ __align__(16) unsigned short Bf[8][512];

    f32x4 acc[4][4];
#pragma unroll
    for (int i = 0; i < 4; ++i)
#pragma unroll
        for (int j = 0; j < 4; ++j) acc[i][j] = (f32x4){0.f, 0.f, 0.f, 0.f};

    const int wm = (w & 1) * 4;
    const int wn = (w >> 1) * 4;

    const unsigned short* aSrc0 = xb + (size_t)(m0 + (w * 2    ) * 16 + l15) * D_ + g * 8;
    const unsigned short* aSrc1 = xb + (size_t)(m0 + (w * 2 + 1) * 16 + l15) * D_ + g * 8;
    const unsigned short* bSrc0 = wb + (size_t)(n0 + (w * 2    ) * 16 + l15) * D_ + g * 8;
    const unsigned short* bSrc1 = wb + (size_t)(n0 + (w * 2 + 1) * 16 + l15) * D_ + g * 8;

    for (int k0 = 0; k0 < D_; k0 += 32) {
        __syncthreads();
        gl2lds16(aSrc0 + k0, &Af[w * 2    ][0]);
        gl2lds16(aSrc1 + k0, &Af[w * 2 + 1][0]);
        gl2lds16(bSrc0 + k0, &Bf[w * 2    ][0]);
        gl2lds16(bSrc1 + k0, &Bf[w * 2 + 1][0]);
        __syncthreads();

        bf16x8 af[4], bf[4];
#pragma unroll
        for (int i = 0; i < 4; ++i) af[i] = *(const bf16x8*)&Af[wm + i][lane * 8];
#pragma unroll
        for (int j = 0; j < 4; ++j) bf[j] = *(const bf16x8*)&Bf[wn + j][lane * 8];

        if (sel < 2) {
#pragma unroll
            for (int i = 0; i < 4; ++i)
#pragma unroll
                for (int j = 0; j < 4; ++j)
                    acc[i][j] = __builtin_amdgcn_mfma_f32_16x16x32_bf16(
                        bf[i], af[j], acc[i][j], 0, 0, 0);
        } else {
#pragma unroll
            for (int i = 0; i < 4; ++i)
#pragma unroll
                for (int j = 0; j < 4; ++j)
                    acc[i][j] = __builtin_amdgcn_mfma_f32_16x16x32_bf16(
                        af[i], bf[j], acc[i][j], 0, 0, 0);
        }
    }

    const size_t BTD = (size_t)B_ * T_ * D_;
    if (sel < 2) {
        unsigned short* out = qkv_out + (size_t)sel * BTD;
#pragma unroll
        for (int i = 0; i < 4; ++i) {
            const int ch0 = n0 + (wn + i) * 16 + g * 4;
            const int h   = ch0 >> 6;
            const int dk0 = ch0 & 63;
            float4 bb = *(const float4*)(bias + ch0);
#pragma unroll
            for (int j = 0; j < 4; ++j) {
                const int tok = m0 + (wm + j) * 16 + l15;
                const int b = tok >> 11, t = tok & (T_ - 1);
                ushort4 r;
                r.x = f2bf((acc[i][j][0] + bb.x) * osc);
                r.y = f2bf((acc[i][j][1] + bb.y) * osc);
                r.z = f2bf((acc[i][j][2] + bb.z) * osc);
                r.w = f2bf((acc[i][j][3] + bb.w) * osc);
                *(ushort4*)(out + ((size_t)((b * H_ + h) * T_ + t)) * DK_ + dk0) = r;
            }
        }
    } else {
        unsigned short* out = qkv_out + 2 * BTD;   // Vt [bh][dk][t]
#pragma unroll
        for (int j = 0; j < 4; ++j) {
            const int ch = n0 + (wn + j) * 16 + l15;
            const int h  = ch >> 6;
            const int dk = ch & 63;
            const float bb = bias[ch];
#pragma unroll
            for (int i = 0; i < 4; ++i) {
                const int tok0 = m0 + (wm + i) * 16 + g * 4;
                const int b = tok0 >> 11, t0 = tok0 & (T_ - 1);
                ushort4 r;
                r.x = f2bf(acc[i][j][0] + bb);
                r.y = f2bf(acc[i][j][1] + bb);
                r.z = f2bf(acc[i][j][2] + bb);
                r.w = f2bf(acc[i][j][3] + bb);
                *(ushort4*)(out + ((size_t)((b * H_ + h) * DK_ + dk)) * T_ + t0) = r;
            }
        }
    }
}

// ---------------------------------------------------------------------------
// MFMA flash attention, R10: SPLIT-K. Fixed-base softmax makes o and l
// linearly decomposable over keys, so blocks process disjoint key ranges and
// a reduce pass sums partials — no rescaling. Grid: per bh, q-tile x covers
// rows x*64..x*64+63; key-splits of 1024: x<16 -> 1 block, x>=16 -> 2 blocks
// (48 per bh, 3072 total, every block <= 16 uniform 64-key chunks).
// R7 wave structure: 4 waves, reg-prefetch staging, lean LDS (6 blocks/CU).
// Outputs fp32 partial o [ks][bh][t][dk] and partial l [ks][bh][t].
// ---------------------------------------------------------------------------
__global__ __launch_bounds__(256) void attn(
    const unsigned short* __restrict__ qg, const unsigned short* __restrict__ kg,
    const unsigned short* __restrict__ vtg,
    float* __restrict__ pO, float* __restrict__ pL)
{
    // heavy-first mapping: ridx descending in work
    const int ridx = 47 - (int)blockIdx.x;
    int x, ks;
    if (ridx < 16) { x = ridx; ks = 0; }
    else { const int r = ridx - 16; x = 16 + (r >> 1); ks = r & 1; }
    const int bh  = blockIdx.y;
    const int tq0 = x * 64;
    const int sBeg = ks << 10;                            // ks * 1024
    const int sEnd = min(sBeg + 1024, tq0 + 64);
    const int nCh  = (sEnd - sBeg) >> 6;                  // 1..16 chunks

    const int tid  = threadIdx.x;
    const int w    = tid >> 6;
    const int lane = tid & 63;
    const int l15  = lane & 15;
    const int g    = lane >> 4;

    const size_t base = (size_t)bh * T_ * DK_;
    const unsigned short* Qb  = qg  + base;   // [t][dk], pre-scaled (0.125*log2e)
    const unsigned short* Kb  = kg  + base;   // [t][dk]
    const unsigned short* Vtb = vtg + base;   // [dk][t]

    __shared__ __align__(16) unsigned short Kf[8][512];     // 8 KB
    __shared__ __align__(16) unsigned short Vf[8][512];     // 8 KB
    __shared__ __align__(16) unsigned short Pb[4][16][68];  // 8.7 KB, 2-way max

    const int q0w = tq0 + w * 16;
    const int tq  = q0w + l15;

    bf16x8 qf0 = *(const bf16x8*)(Qb + (size_t)tq * DK_ + g * 8);
    bf16x8 qf1 = *(const bf16x8*)(Qb + (size_t)tq * DK_ + 32 + g * 8);

    f32x4 o[4];
#pragma unroll
    for (int i = 0; i < 4; ++i) o[i] = (f32x4){0.f, 0.f, 0.f, 0.f};
    float lrun = 0.f;

    // wave w stages K s-tile st=w and V d-tile dt=w (both 32-wide halves)
    const unsigned short* kSrc = Kb + (size_t)(sBeg + w * 16 + l15) * DK_ + g * 8;
    const unsigned short* vSrc = Vtb + (size_t)(w * 16 + l15) * T_ + sBeg + g * 8;

    // preload chunk 0 into registers
    bf16x8 kr0 = *(const bf16x8*)(kSrc);
    bf16x8 kr1 = *(const bf16x8*)(kSrc + 32);
    bf16x8 vr0 = *(const bf16x8*)(vSrc);
    bf16x8 vr1 = *(const bf16x8*)(vSrc + 32);

    for (int ch = 0; ch < nCh; ++ch) {
        const int s0 = sBeg + ch * 64;
        __syncthreads();                       // previous chunk fully consumed
        *(bf16x8*)&Kf[2 * w    ][lane * 8] = kr0;
        *(bf16x8*)&Kf[2 * w + 1][lane * 8] = kr1;
        *(bf16x8*)&Vf[2 * w    ][lane * 8] = vr0;
        *(bf16x8*)&Vf[2 * w + 1][lane * 8] = vr1;
        if (ch + 1 < nCh) {                    // loads stay in flight across barrier
            const size_t ko = (size_t)(ch + 1) * 64 * DK_;
            const int    vo = (ch + 1) * 64;
            kr0 = *(const bf16x8*)(kSrc + ko);
            kr1 = *(const bf16x8*)(kSrc + ko + 32);
            vr0 = *(const bf16x8*)(vSrc + vo);
            vr1 = *(const bf16x8*)(vSrc + vo + 32);
        }
        __syncthreads();                       // staged data visible

        float ps = 0.f;
#pragma unroll
        for (int st = 0; st < 4; ++st) {
            const int sbase = s0 + st * 16;
            const bool live = (sbase <= q0w + 15);
            ushort4 pk;
            if (live) {
                bf16x8 a0 = *(const bf16x8*)&Kf[st * 2 + 0][lane * 8];
                bf16x8 a1 = *(const bf16x8*)&Kf[st * 2 + 1][lane * 8];
                f32x4 sacc = {0.f, 0.f, 0.f, 0.f};
                sacc = __builtin_amdgcn_mfma_f32_16x16x32_bf16(a0, qf0, sacc, 0, 0, 0);
                sacc = __builtin_amdgcn_mfma_f32_16x16x32_bf16(a1, qf1, sacc, 0, 0, 0);
                float p0, p1, p2, p3;
                if (sbase + 15 > q0w) {        // diagonal tile: per-entry mask
                    p0 = (sbase + g * 4 + 0 <= tq) ? exp2f(sacc[0]) : 0.f;
                    p1 = (sbase + g * 4 + 1 <= tq) ? exp2f(sacc[1]) : 0.f;
                    p2 = (sbase + g * 4 + 2 <= tq) ? exp2f(sacc[2]) : 0.f;
                    p3 = (sbase + g * 4 + 3 <= tq) ? exp2f(sacc[3]) : 0.f;
                } else {                       // fully unmasked
                    p0 = exp2f(sacc[0]); p1 = exp2f(sacc[1]);
                    p2 = exp2f(sacc[2]); p3 = exp2f(sacc[3]);
                }
                ps += (p0 + p1) + (p2 + p3);
                pk.x = f2bf(p0); pk.y = f2bf(p1); pk.z = f2bf(p2); pk.w = f2bf(p3);
            } else {
                pk.x = 0; pk.y = 0; pk.z = 0; pk.w = 0;
            }
            *(ushort4*)&Pb[w][l15][st * 16 + g * 4] = pk;   // P[q][s], s-contig
        }

        ps += __shfl_xor(ps, 16, 64);
        ps += __shfl_xor(ps, 32, 64);
        lrun += ps;

        bf16x8 pf0 = *(const bf16x8*)&Pb[w][l15][g * 8];        // k = s 0..31
        bf16x8 pf1 = *(const bf16x8*)&Pb[w][l15][32 + g * 8];   // k = s 32..63
#pragma unroll
        for (int dt = 0; dt < 4; ++dt) {
            bf16x8 v0 = *(const bf16x8*)&Vf[dt * 2 + 0][lane * 8];
            bf16x8 v1 = *(const bf16x8*)&Vf[dt * 2 + 1][lane * 8];
            o[dt] = __builtin_amdgcn_mfma_f32_16x16x32_bf16(v0, pf0, o[dt], 0, 0, 0);
            o[dt] = __builtin_amdgcn_mfma_f32_16x16x32_bf16(v1, pf1, o[dt], 0, 0, 0);
        }
    }

    // partial output: fp32 o (un-normalized) + l for this key range
    float* po = pO + ((size_t)ks * (B_ * H_) + bh) * (size_t)T_ * DK_
                   + (size_t)tq * DK_;
#pragma unroll
    for (int dt = 0; dt < 4; ++dt) {
        float4 r;
        r.x = o[dt][0]; r.y = o[dt][1]; r.z = o[dt][2]; r.w = o[dt][3];
        *(float4*)(po + dt * 16 + g * 4) = r;
    }
    if (g == 0)
        pL[((size_t)ks * (B_ * H_) + bh) * T_ + tq] = lrun;
}

// ---------------------------------------------------------------------------
// Split-K reduce: o = sum of active split partials, yh = bf16(o / sum l).
// Split ks=1 is active only for t >= 1024. One float4 per thread.
// ---------------------------------------------------------------------------
__global__ __launch_bounds__(256) void attn_reduce(
    const float* __restrict__ pO, const float* __restrict__ pL,
    unsigned short* __restrict__ yh)
{
    const int idx  = blockIdx.x * 256 + threadIdx.x;   // float4 index over B*H*T*DK/4
    const int flat = idx * 4;
    const int dk = flat & 63;
    const int t  = (flat >> 6) & (T_ - 1);
    const int bh = flat >> 17;                         // /(T_*DK_)
    const int h = bh & (H_ - 1), b = bh >> 4;

    float4 o = ((const float4*)pO)[idx];
    float  l = pL[(size_t)bh * T_ + t];
    if (t >= 1024) {
        const size_t soff = (size_t)(B_ * H_) * T_ * DK_ / 4;
        float4 o1 = ((const float4*)pO)[soff + idx];
        o.x += o1.x; o.y += o1.y; o.z += o1.z; o.w += o1.w;
        l += pL[(size_t)(B_ * H_) * T_ + (size_t)bh * T_ + t];
    }
    const float inv = 1.f / l;
    ushort4 r;
    r.x = f2bf(o.x * inv); r.y = f2bf(o.y * inv);
    r.z = f2bf(o.z * inv); r.w = f2bf(o.w * inv);
    *(ushort4*)(yh + ((size_t)(b * T_ + t)) * D_ + h * DK_ + dk) = r;
}

// ---------------------------------------------------------------------------
// Output MFMA GEMM: out[tok][ch] fp32 = yhb . wob^T + bo. (unchanged)
// ---------------------------------------------------------------------------
__global__ __launch_bounds__(256) void out_gemm(
    const unsigned short* __restrict__ yhb, const unsigned short* __restrict__ wob,
    const float* __restrict__ bo, float* __restrict__ out)
{
    const int m0 = blockIdx.x * 128;
    const int n0 = blockIdx.y * 128;
    const int tid = threadIdx.x;
    const int w = tid >> 6, lane = tid & 63;
    const int l15 = lane & 15, g = lane >> 4;

    __shared__ __align__(16) unsigned short Af[8][512];
    __shared__ __align__(16) unsigned short Bf[8][512];

    f32x4 acc[4][4];
#pragma unroll
    for (int i = 0; i < 4; ++i)
#pragma unroll
        for (int j = 0; j < 4; ++j) acc[i][j] = (f32x4){0.f, 0.f, 0.f, 0.f};

    const int wm = (w & 1) * 4;
    const int wn = (w >> 1) * 4;

    const unsigned short* aSrc0 = yhb + (size_t)(m0 + (w * 2    ) * 16 + l15) * D_ + g * 8;
    const unsigned short* aSrc1 = yhb + (size_t)(m0 + (w * 2 + 1) * 16 + l15) * D_ + g * 8;
    const unsigned short* bSrc0 = wob + (size_t)(n0 + (w * 2    ) * 16 + l15) * D_ + g * 8;
    const unsigned short* bSrc1 = wob + (size_t)(n0 + (w * 2 + 1) * 16 + l15) * D_ + g * 8;

    for (int k0 = 0; k0 < D_; k0 += 32) {
        __syncthreads();
        gl2lds16(aSrc0 + k0, &Af[w * 2    ][0]);
        gl2lds16(aSrc1 + k0, &Af[w * 2 + 1][0]);
        gl2lds16(bSrc0 + k0, &Bf[w * 2    ][0]);
        gl2lds16(bSrc1 + k0, &Bf[w * 2 + 1][0]);
        __syncthreads();

        bf16x8 af[4], bf[4];
#pragma unroll
        for (int i = 0; i < 4; ++i) af[i] = *(const bf16x8*)&Af[wm + i][lane * 8];
#pragma unroll
        for (int j = 0; j < 4; ++j) bf[j] = *(const bf16x8*)&Bf[wn + j][lane * 8];

#pragma unroll
        for (int i = 0; i < 4; ++i)
#pragma unroll
            for (int j = 0; j < 4; ++j)
                acc[i][j] = __builtin_amdgcn_mfma_f32_16x16x32_bf16(
                    bf[i], af[j], acc[i][j], 0, 0, 0);
    }

#pragma unroll
    for (int i = 0; i < 4; ++i) {
        const int ch0 = n0 + (wn + i) * 16 + g * 4;
        float4 bb = *(const float4*)(bo + ch0);
#pragma unroll
        for (int j = 0; j < 4; ++j) {
            const int tok = m0 + (wm + j) * 16 + l15;
            float4 r;
            r.x = acc[i][j][0] + bb.x;
            r.y = acc[i][j][1] + bb.y;
            r.z = acc[i][j][2] + bb.z;
            r.w = acc[i][j][3] + bb.w;
            *(float4*)(out + (size_t)tok * D_ + ch0) = r;
        }
    }
}

// ---------------------------------------------------------------------------
extern "C" void kernel_launch(void* const* d_in, const int* in_sizes, int n_in,
                              void* d_out, int out_size, void* d_ws, size_t ws_size,
                              hipStream_t stream) {
    const float* x  = (const float*)d_in[0];
    const float* wq = (const float*)d_in[1];
    const float* bq = (const float*)d_in[2];
    const float* wk = (const float*)d_in[3];
    const float* bk = (const float*)d_in[4];
    const float* wv = (const float*)d_in[5];
    const float* bv = (const float*)d_in[6];
    const float* wo = (const float*)d_in[7];
    const float* bo = (const float*)d_in[8];
    float* out = (float*)d_out;

    const size_t BTD = (size_t)B_ * T_ * D_;          // 8388608
    const size_t WSZ = (size_t)D_ * D_;               // 1048576
    unsigned short* xb  = (unsigned short*)d_ws;      // [x | wq | wk | wv | wo] bf16
    unsigned short* wqb = xb  + BTD;
    unsigned short* wkb = wqb + WSZ;
    unsigned short* wvb = wkb + WSZ;
    unsigned short* wob = wvb + WSZ;
    unsigned short* qb  = wob + WSZ;                  // q | k | vt bf16
    unsigned short* kb  = qb  + BTD;
    unsigned short* vtb = kb  + BTD;
    unsigned short* yhb = vtb + BTD;                  // yh bf16 [B,T,D]
    float* pO = (float*)(yhb + BTD);                  // [2][bh][t][dk] fp32, 67 MB
    float* pL = pO + 2 * BTD;                         // [2][bh][t] fp32, 1 MB
    // total ws ~ 160 MB

    cvt_bf16<<<dim3(12288), 256, 0, stream>>>(x, wq, wk, wv, wo, xb);

    dim3 g1(M_ / 128, D_ / 128, 3);
    qkv_gemm<<<g1, 256, 0, stream>>>(xb, wqb, wkb, wvb, bq, bk, bv, qb);

    dim3 g2(48, B_ * H_);                             // 3072 blocks, uniform work
    attn<<<g2, 256, 0, stream>>>(qb, kb, vtb, pO, pL);

    attn_reduce<<<dim3((int)(BTD / 4 / 256)), 256, 0, stream>>>(pO, pL, yhb);

    dim3 g3(M_ / 128, D_ / 128);
    out_gemm<<<g3, 256, 0, stream>>>(yhb, wob, bo, out);
}

// Round 11
// 351.491 us; speedup vs baseline: 1.1115x; 1.0251x over previous
//
#include <hip/hip_runtime.h>
#include <hip/hip_bf16.h>
#include <cstdint>
#include <cstddef>

#define B_  4
#define T_  2048
#define D_  1024
#define H_  16
#define DK_ 64
#define M_  (B_ * T_)     // 8192 tokens

typedef __attribute__((ext_vector_type(8))) short bf16x8;   // MFMA A/B frag (4 VGPRs)
typedef __attribute__((ext_vector_type(4))) float f32x4;    // MFMA C/D frag

static __device__ __forceinline__ unsigned short f2bf(float f) {
    __hip_bfloat16 h = __float2bfloat16(f);
    unsigned short u;
    __builtin_memcpy(&u, &h, 2);
    return u;
}

static __device__ __forceinline__ unsigned int pk2bf(float a, float b) {
    __hip_bfloat162 h = __float22bfloat162_rn(make_float2(a, b));
    unsigned int u;
    __builtin_memcpy(&u, &h, 4);
    return u;
}

static __device__ __forceinline__ void gl2lds16(const void* g, void* l) {
    __builtin_amdgcn_global_load_lds(
        (const __attribute__((address_space(1))) unsigned int*)g,
        (__attribute__((address_space(3))) unsigned int*)l,
        16, 0, 0);
}

// ---------------------------------------------------------------------------
// fp32 -> bf16 convert: regions [x | wq | wk | wv | wo] -> contiguous dst.
// ---------------------------------------------------------------------------
__global__ __launch_bounds__(256) void cvt_bf16(
    const float* __restrict__ x,  const float* __restrict__ wq,
    const float* __restrict__ wk, const float* __restrict__ wv,
    const float* __restrict__ wo, unsigned short* __restrict__ dst)
{
    const int idx = blockIdx.x * 256 + threadIdx.x;   // vec4 index
    const float* src;
    int off;
    if (idx < 2097152) { src = x; off = idx; }
    else {
        const int r = (idx - 2097152) >> 18;
        off = (idx - 2097152) & 262143;
        src = (r == 0) ? wq : (r == 1) ? wk : (r == 2) ? wv : wo;
    }
    float4 v = ((const float4*)src)[off];
    ushort4 o;
    o.x = f2bf(v.x); o.y = f2bf(v.y); o.z = f2bf(v.z); o.w = f2bf(v.w);
    ((ushort4*)dst)[idx] = o;
}

// ---------------------------------------------------------------------------
// QKV MFMA GEMM (m97 structure), 128x128 tile, BK=32.
// Q epilogue folds 1/sqrt(DK) * log2(e) so attention uses raw exp2.
// ---------------------------------------------------------------------------
__global__ __launch_bounds__(256) void qkv_gemm(
    const unsigned short* __restrict__ xb,
    const unsigned short* __restrict__ wqb, const unsigned short* __restrict__ wkb,
    const unsigned short* __restrict__ wvb,
    const float* __restrict__ bq, const float* __restrict__ bk,
    const float* __restrict__ bv,
    unsigned short* __restrict__ qkv_out)
{
    const int sel = blockIdx.z;
    const unsigned short* wb = (sel == 0) ? wqb : (sel == 1) ? wkb : wvb;
    const float* bias        = (sel == 0) ? bq  : (sel == 1) ? bk  : bv;
    const float osc          = (sel == 0) ? 0.125f * 1.44269504f : 1.0f;

    const int m0 = blockIdx.x * 128;
    const int n0 = blockIdx.y * 128;
    const int tid = threadIdx.x;
    const int w = tid >> 6, lane = tid & 63;
    const int l15 = lane & 15, g = lane >> 4;

    __shared__ __align__(16) unsigned short Af[8][512];
    __shared__ __align__(16) unsigned short Bf[8][512];

    f32x4 acc[4][4];
#pragma unroll
    for (int i = 0; i < 4; ++i)
#pragma unroll
        for (int j = 0; j < 4; ++j) acc[i][j] = (f32x4){0.f, 0.f, 0.f, 0.f};

    const int wm = (w & 1) * 4;
    const int wn = (w >> 1) * 4;

    const unsigned short* aSrc0 = xb + (size_t)(m0 + (w * 2    ) * 16 + l15) * D_ + g * 8;
    const unsigned short* aSrc1 = xb + (size_t)(m0 + (w * 2 + 1) * 16 + l15) * D_ + g * 8;
    const unsigned short* bSrc0 = wb + (size_t)(n0 + (w * 2    ) * 16 + l15) * D_ + g * 8;
    const unsigned short* bSrc1 = wb + (size_t)(n0 + (w * 2 + 1) * 16 + l15) * D_ + g * 8;

    for (int k0 = 0; k0 < D_; k0 += 32) {
        __syncthreads();
        gl2lds16(aSrc0 + k0, &Af[w * 2    ][0]);
        gl2lds16(aSrc1 + k0, &Af[w * 2 + 1][0]);
        gl2lds16(bSrc0 + k0, &Bf[w * 2    ][0]);
        gl2lds16(bSrc1 + k0, &Bf[w * 2 + 1][0]);
        __syncthreads();

        bf16x8 af[4], bf[4];
#pragma unroll
        for (int i = 0; i < 4; ++i) af[i] = *(const bf16x8*)&Af[wm + i][lane * 8];
#pragma unroll
        for (int j = 0; j < 4; ++j) bf[j] = *(const bf16x8*)&Bf[wn + j][lane * 8];

        if (sel < 2) {
#pragma unroll
            for (int i = 0; i < 4; ++i)
#pragma unroll
                for (int j = 0; j < 4; ++j)
                    acc[i][j] = __builtin_amdgcn_mfma_f32_16x16x32_bf16(
                        bf[i], af[j], acc[i][j], 0, 0, 0);
        } else {
#pragma unroll
            for (int i = 0; i < 4; ++i)
#pragma unroll
                for (int j = 0; j < 4; ++j)
                    acc[i][j] = __builtin_amdgcn_mfma_f32_16x16x32_bf16(
                        af[i], bf[j], acc[i][j], 0, 0, 0);
        }
    }

    const size_t BTD = (size_t)B_ * T_ * D_;
    if (sel < 2) {
        unsigned short* out = qkv_out + (size_t)sel * BTD;
#pragma unroll
        for (int i = 0; i < 4; ++i) {
            const int ch0 = n0 + (wn + i) * 16 + g * 4;
            const int h   = ch0 >> 6;
            const int dk0 = ch0 & 63;
            float4 bb = *(const float4*)(bias + ch0);
#pragma unroll
            for (int j = 0; j < 4; ++j) {
                const int tok = m0 + (wm + j) * 16 + l15;
                const int b = tok >> 11, t = tok & (T_ - 1);
                ushort4 r;
                r.x = f2bf((acc[i][j][0] + bb.x) * osc);
                r.y = f2bf((acc[i][j][1] + bb.y) * osc);
                r.z = f2bf((acc[i][j][2] + bb.z) * osc);
                r.w = f2bf((acc[i][j][3] + bb.w) * osc);
                *(ushort4*)(out + ((size_t)((b * H_ + h) * T_ + t)) * DK_ + dk0) = r;
            }
        }
    } else {
        unsigned short* out = qkv_out + 2 * BTD;   // Vt [bh][dk][t]
#pragma unroll
        for (int j = 0; j < 4; ++j) {
            const int ch = n0 + (wn + j) * 16 + l15;
            const int h  = ch >> 6;
            const int dk = ch & 63;
            const float bb = bias[ch];
#pragma unroll
            for (int i = 0; i < 4; ++i) {
                const int tok0 = m0 + (wm + i) * 16 + g * 4;
                const int b = tok0 >> 11, t0 = tok0 & (T_ - 1);
                ushort4 r;
                r.x = f2bf(acc[i][j][0] + bb);
                r.y = f2bf(acc[i][j][1] + bb);
                r.z = f2bf(acc[i][j][2] + bb);
                r.w = f2bf(acc[i][j][3] + bb);
                *(ushort4*)(out + ((size_t)((b * H_ + h) * DK_ + dk)) * T_ + t0) = r;
            }
        }
    }
}

// ---------------------------------------------------------------------------
// MFMA flash attention, R11: split-K (fixed-base softmax is key-linear) +
// VALU diet: l computed by an all-ones MFMA A-fragment (D[.][q] = sum_s P[s][q]
// lands in exactly the lane owning q), packed bf16x2 P conversion, and
// single-split blocks (t < 1024) normalize + write bf16 yh directly —
// pO/pL partials only for t >= 1024 (two key-splits).
// R7 wave structure: 4 waves x 16 q, register-prefetch staging, lean LDS.
// ---------------------------------------------------------------------------
__global__ __launch_bounds__(256) void attn(
    const unsigned short* __restrict__ qg, const unsigned short* __restrict__ kg,
    const unsigned short* __restrict__ vtg,
    float* __restrict__ pO, float* __restrict__ pL,
    unsigned short* __restrict__ yh)
{
    // heavy-first mapping: ridx descending in work
    const int ridx = 47 - (int)blockIdx.x;
    int x, ks;
    if (ridx < 16) { x = ridx; ks = 0; }
    else { const int r = ridx - 16; x = 16 + (r >> 1); ks = r & 1; }
    const int bh  = blockIdx.y;
    const int h   = bh & (H_ - 1);
    const int b   = bh >> 4;
    const int tq0 = x * 64;
    const int sBeg = ks << 10;                            // ks * 1024
    const int sEnd = min(sBeg + 1024, tq0 + 64);
    const int nCh  = (sEnd - sBeg) >> 6;                  // 1..16 chunks

    const int tid  = threadIdx.x;
    const int w    = tid >> 6;
    const int lane = tid & 63;
    const int l15  = lane & 15;
    const int g    = lane >> 4;

    const size_t base = (size_t)bh * T_ * DK_;
    const unsigned short* Qb  = qg  + base;   // [t][dk], pre-scaled (0.125*log2e)
    const unsigned short* Kb  = kg  + base;   // [t][dk]
    const unsigned short* Vtb = vtg + base;   // [dk][t]

    __shared__ __align__(16) unsigned short Kf[8][512];     // 8 KB
    __shared__ __align__(16) unsigned short Vf[8][512];     // 8 KB
    __shared__ __align__(16) unsigned short Pb[4][16][68];  // 8.7 KB, 2-way max

    const int q0w = tq0 + w * 16;
    const int tq  = q0w + l15;

    bf16x8 qf0 = *(const bf16x8*)(Qb + (size_t)tq * DK_ + g * 8);
    bf16x8 qf1 = *(const bf16x8*)(Qb + (size_t)tq * DK_ + 32 + g * 8);

    // all-ones A fragment (bf16 1.0 = 0x3F80) for the l-sum MFMA
    bf16x8 ones;
#pragma unroll
    for (int j = 0; j < 8; ++j) ones[j] = (short)0x3F80;

    f32x4 o[4];
#pragma unroll
    for (int i = 0; i < 4; ++i) o[i] = (f32x4){0.f, 0.f, 0.f, 0.f};
    f32x4 lacc = {0.f, 0.f, 0.f, 0.f};

    // wave w stages K s-tile st=w and V d-tile dt=w (both 32-wide halves)
    const unsigned short* kSrc = Kb + (size_t)(sBeg + w * 16 + l15) * DK_ + g * 8;
    const unsigned short* vSrc = Vtb + (size_t)(w * 16 + l15) * T_ + sBeg + g * 8;

    // preload chunk 0 into registers
    bf16x8 kr0 = *(const bf16x8*)(kSrc);
    bf16x8 kr1 = *(const bf16x8*)(kSrc + 32);
    bf16x8 vr0 = *(const bf16x8*)(vSrc);
    bf16x8 vr1 = *(const bf16x8*)(vSrc + 32);

    for (int ch = 0; ch < nCh; ++ch) {
        const int s0 = sBeg + ch * 64;
        __syncthreads();                       // previous chunk fully consumed
        *(bf16x8*)&Kf[2 * w    ][lane * 8] = kr0;
        *(bf16x8*)&Kf[2 * w + 1][lane * 8] = kr1;
        *(bf16x8*)&Vf[2 * w    ][lane * 8] = vr0;
        *(bf16x8*)&Vf[2 * w + 1][lane * 8] = vr1;
        if (ch + 1 < nCh) {                    // loads stay in flight across barrier
            const size_t ko = (size_t)(ch + 1) * 64 * DK_;
            const int    vo = (ch + 1) * 64;
            kr0 = *(const bf16x8*)(kSrc + ko);
            kr1 = *(const bf16x8*)(kSrc + ko + 32);
            vr0 = *(const bf16x8*)(vSrc + vo);
            vr1 = *(const bf16x8*)(vSrc + vo + 32);
        }
        __syncthreads();                       // staged data visible

#pragma unroll
        for (int st = 0; st < 4; ++st) {
            const int sbase = s0 + st * 16;
            const bool live = (sbase <= q0w + 15);
            unsigned int pkl, pkh;
            if (live) {
                bf16x8 a0 = *(const bf16x8*)&Kf[st * 2 + 0][lane * 8];
                bf16x8 a1 = *(const bf16x8*)&Kf[st * 2 + 1][lane * 8];
                f32x4 sacc = {0.f, 0.f, 0.f, 0.f};
                sacc = __builtin_amdgcn_mfma_f32_16x16x32_bf16(a0, qf0, sacc, 0, 0, 0);
                sacc = __builtin_amdgcn_mfma_f32_16x16x32_bf16(a1, qf1, sacc, 0, 0, 0);
                float p0, p1, p2, p3;
                if (sbase + 15 > q0w) {        // diagonal tile: per-entry mask
                    p0 = (sbase + g * 4 + 0 <= tq) ? exp2f(sacc[0]) : 0.f;
                    p1 = (sbase + g * 4 + 1 <= tq) ? exp2f(sacc[1]) : 0.f;
                    p2 = (sbase + g * 4 + 2 <= tq) ? exp2f(sacc[2]) : 0.f;
                    p3 = (sbase + g * 4 + 3 <= tq) ? exp2f(sacc[3]) : 0.f;
                } else {                       // fully unmasked
                    p0 = exp2f(sacc[0]); p1 = exp2f(sacc[1]);
                    p2 = exp2f(sacc[2]); p3 = exp2f(sacc[3]);
                }
                pkl = pk2bf(p0, p1);
                pkh = pk2bf(p2, p3);
            } else {
                pkl = 0; pkh = 0;
            }
            uint2 pk; pk.x = pkl; pk.y = pkh;
            *(uint2*)&Pb[w][l15][st * 16 + g * 4] = pk;     // P[q][s], s-contig
        }

        bf16x8 pf0 = *(const bf16x8*)&Pb[w][l15][g * 8];        // k = s 0..31
        bf16x8 pf1 = *(const bf16x8*)&Pb[w][l15][32 + g * 8];   // k = s 32..63
        lacc = __builtin_amdgcn_mfma_f32_16x16x32_bf16(ones, pf0, lacc, 0, 0, 0);
        lacc = __builtin_amdgcn_mfma_f32_16x16x32_bf16(ones, pf1, lacc, 0, 0, 0);
#pragma unroll
        for (int dt = 0; dt < 4; ++dt) {
            bf16x8 v0 = *(const bf16x8*)&Vf[dt * 2 + 0][lane * 8];
            bf16x8 v1 = *(const bf16x8*)&Vf[dt * 2 + 1][lane * 8];
            o[dt] = __builtin_amdgcn_mfma_f32_16x16x32_bf16(v0, pf0, o[dt], 0, 0, 0);
            o[dt] = __builtin_amdgcn_mfma_f32_16x16x32_bf16(v1, pf1, o[dt], 0, 0, 0);
        }
    }

    if (tq0 < 1024) {
        // single split: normalize and write yh bf16 directly
        const float inv = 1.f / lacc[0];
        unsigned short* yrow = yh + ((size_t)(b * T_ + tq)) * D_ + h * DK_;
#pragma unroll
        for (int dt = 0; dt < 4; ++dt) {
            ushort4 r;
            r.x = f2bf(o[dt][0] * inv); r.y = f2bf(o[dt][1] * inv);
            r.z = f2bf(o[dt][2] * inv); r.w = f2bf(o[dt][3] * inv);
            *(ushort4*)(yrow + dt * 16 + g * 4) = r;
        }
    } else {
        // two splits: write fp32 partials for the reduce pass
        float* po = pO + ((size_t)ks * (B_ * H_) + bh) * (size_t)T_ * DK_
                       + (size_t)tq * DK_;
#pragma unroll
        for (int dt = 0; dt < 4; ++dt) {
            float4 r;
            r.x = o[dt][0]; r.y = o[dt][1]; r.z = o[dt][2]; r.w = o[dt][3];
            *(float4*)(po + dt * 16 + g * 4) = r;
        }
        if (g == 0)
            pL[((size_t)ks * (B_ * H_) + bh) * T_ + tq] = lacc[0];
    }
}

// ---------------------------------------------------------------------------
// Split-K reduce, t >= 1024 only: o = o0 + o1, yh = bf16(o / (l0 + l1)).
// ---------------------------------------------------------------------------
__global__ __launch_bounds__(256) void attn_reduce(
    const float* __restrict__ pO, const float* __restrict__ pL,
    unsigned short* __restrict__ yh)
{
    const int idx  = blockIdx.x * 256 + threadIdx.x;   // float4 idx over [bh][1024][64]
    const int flat = idx * 4;
    const int dk = flat & 63;
    const int t  = 1024 + ((flat >> 6) & 1023);
    const int bh = flat >> 16;
    const int h = bh & (H_ - 1), b = bh >> 4;

    const size_t e0 = ((size_t)bh * T_ + t) * DK_ + dk;
    const size_t soff = (size_t)(B_ * H_) * T_ * DK_;
    float4 o  = *(const float4*)(pO + e0);
    float4 o1 = *(const float4*)(pO + soff + e0);
    o.x += o1.x; o.y += o1.y; o.z += o1.z; o.w += o1.w;
    const float l = pL[(size_t)bh * T_ + t]
                  + pL[(size_t)(B_ * H_) * T_ + (size_t)bh * T_ + t];
    const float inv = 1.f / l;
    ushort4 r;
    r.x = f2bf(o.x * inv); r.y = f2bf(o.y * inv);
    r.z = f2bf(o.z * inv); r.w = f2bf(o.w * inv);
    *(ushort4*)(yh + ((size_t)(b * T_ + t)) * D_ + h * DK_ + dk) = r;
}

// ---------------------------------------------------------------------------
// Output MFMA GEMM: out[tok][ch] fp32 = yhb . wob^T + bo. (unchanged)
// ---------------------------------------------------------------------------
__global__ __launch_bounds__(256) void out_gemm(
    const unsigned short* __restrict__ yhb, const unsigned short* __restrict__ wob,
    const float* __restrict__ bo, float* __restrict__ out)
{
    const int m0 = blockIdx.x * 128;
    const int n0 = blockIdx.y * 128;
    const int tid = threadIdx.x;
    const int w = tid >> 6, lane = tid & 63;
    const int l15 = lane & 15, g = lane >> 4;

    __shared__ __align__(16) unsigned short Af[8][512];
    __shared__ __align__(16) unsigned short Bf[8][512];

    f32x4 acc[4][4];
#pragma unroll
    for (int i = 0; i < 4; ++i)
#pragma unroll
        for (int j = 0; j < 4; ++j) acc[i][j] = (f32x4){0.f, 0.f, 0.f, 0.f};

    const int wm = (w & 1) * 4;
    const int wn = (w >> 1) * 4;

    const unsigned short* aSrc0 = yhb + (size_t)(m0 + (w * 2    ) * 16 + l15) * D_ + g * 8;
    const unsigned short* aSrc1 = yhb + (size_t)(m0 + (w * 2 + 1) * 16 + l15) * D_ + g * 8;
    const unsigned short* bSrc0 = wob + (size_t)(n0 + (w * 2    ) * 16 + l15) * D_ + g * 8;
    const unsigned short* bSrc1 = wob + (size_t)(n0 + (w * 2 + 1) * 16 + l15) * D_ + g * 8;

    for (int k0 = 0; k0 < D_; k0 += 32) {
        __syncthreads();
        gl2lds16(aSrc0 + k0, &Af[w * 2    ][0]);
        gl2lds16(aSrc1 + k0, &Af[w * 2 + 1][0]);
        gl2lds16(bSrc0 + k0, &Bf[w * 2    ][0]);
        gl2lds16(bSrc1 + k0, &Bf[w * 2 + 1][0]);
        __syncthreads();

        bf16x8 af[4], bf[4];
#pragma unroll
        for (int i = 0; i < 4; ++i) af[i] = *(const bf16x8*)&Af[wm + i][lane * 8];
#pragma unroll
        for (int j = 0; j < 4; ++j) bf[j] = *(const bf16x8*)&Bf[wn + j][lane * 8];

#pragma unroll
        for (int i = 0; i < 4; ++i)
#pragma unroll
            for (int j = 0; j < 4; ++j)
                acc[i][j] = __builtin_amdgcn_mfma_f32_16x16x32_bf16(
                    bf[i], af[j], acc[i][j], 0, 0, 0);
    }

#pragma unroll
    for (int i = 0; i < 4; ++i) {
        const int ch0 = n0 + (wn + i) * 16 + g * 4;
        float4 bb = *(const float4*)(bo + ch0);
#pragma unroll
        for (int j = 0; j < 4; ++j) {
            const int tok = m0 + (wm + j) * 16 + l15;
            float4 r;
            r.x = acc[i][j][0] + bb.x;
            r.y = acc[i][j][1] + bb.y;
            r.z = acc[i][j][2] + bb.z;
            r.w = acc[i][j][3] + bb.w;
            *(float4*)(out + (size_t)tok * D_ + ch0) = r;
        }
    }
}

// ---------------------------------------------------------------------------
extern "C" void kernel_launch(void* const* d_in, const int* in_sizes, int n_in,
                              void* d_out, int out_size, void* d_ws, size_t ws_size,
                              hipStream_t stream) {
    const float* x  = (const float*)d_in[0];
    const float* wq = (const float*)d_in[1];
    const float* bq = (const float*)d_in[2];
    const float* wk = (const float*)d_in[3];
    const float* bk = (const float*)d_in[4];
    const float* wv = (const float*)d_in[5];
    const float* bv = (const float*)d_in[6];
    const float* wo = (const float*)d_in[7];
    const float* bo = (const float*)d_in[8];
    float* out = (float*)d_out;

    const size_t BTD = (size_t)B_ * T_ * D_;          // 8388608
    const size_t WSZ = (size_t)D_ * D_;               // 1048576
    unsigned short* xb  = (unsigned short*)d_ws;      // [x | wq | wk | wv | wo] bf16
    unsigned short* wqb = xb  + BTD;
    unsigned short* wkb = wqb + WSZ;
    unsigned short* wvb = wkb + WSZ;
    unsigned short* wob = wvb + WSZ;
    unsigned short* qb  = wob + WSZ;                  // q | k | vt bf16
    unsigned short* kb  = qb  + BTD;
    unsigned short* vtb = kb  + BTD;
    unsigned short* yhb = vtb + BTD;                  // yh bf16 [B,T,D]
    float* pO = (float*)(yhb + BTD);                  // [2][bh][t][dk] fp32
    float* pL = pO + 2 * BTD;                         // [2][bh][t] fp32

    cvt_bf16<<<dim3(12288), 256, 0, stream>>>(x, wq, wk, wv, wo, xb);

    dim3 g1(M_ / 128, D_ / 128, 3);
    qkv_gemm<<<g1, 256, 0, stream>>>(xb, wqb, wkb, wvb, bq, bk, bv, qb);

    dim3 g2(48, B_ * H_);                             // 3072 blocks, uniform work
    attn<<<g2, 256, 0, stream>>>(qb, kb, vtb, pO, pL, yhb);

    // reduce only t >= 1024: 64 bh * 1024 t * 64 dk / 4 / 256 = 4096 blocks
    attn_reduce<<<dim3(4096), 256, 0, stream>>>(pO, pL, yhb);

    dim3 g3(M_ / 128, D_ / 128);
    out_gemm<<<g3, 256, 0, stream>>>(yhb, wob, bo, out);
}